// Round 7
// baseline (3130.260 us; speedup 1.0000x reference)
//
#include <hip/hip_runtime.h>
#include <hip/hip_cooperative_groups.h>

namespace cg = cooperative_groups;

#define LL 256
#define BB 128
#define NLEV 48

// Agent-scope seq_cst fence: writeback + invalidate L1/L2 (cross-XCD visibility).
#define DEV_FENCE() __builtin_amdgcn_fence(__ATOMIC_SEQ_CST, "agent")

typedef float  floatx4 __attribute__((ext_vector_type(4)));
typedef short  short8  __attribute__((ext_vector_type(8)));

struct Params {
  const float* inputs;
  const float* ioux_w[2]; const float* ioux_b[2];
  const float* iouh_w[2]; const float* iouh_b[2];
  const float* fx_w[2];   const float* fx_b[2];
  const float* fh_w[2];   const float* fh_b[2];
};

__device__ __forceinline__ unsigned short f2bf(float f) {
  unsigned u = __float_as_uint(f);
  u += 0x7fffu + ((u >> 16) & 1u);
  return (unsigned short)(u >> 16);
}
__device__ __forceinline__ float bf2f(unsigned u) { return __uint_as_float(u << 16); }
__device__ __forceinline__ float sigm(float x) { return 1.0f / (1.0f + __expf(-x)); }
__device__ __forceinline__ float tanh_(float x) { return 1.0f - 2.0f / (1.0f + __expf(2.0f * x)); }

// ---------------------------------------------------------------------------
// prep: bf16 inputs; bf16 x-weights and h-weights in natural gate-planar rows
// cc = g*256+j (rows 0..767 = iou, 768..1023 = f); folded bias[d][1024].
// ---------------------------------------------------------------------------
__global__ __launch_bounds__(256) void prep_kernel(Params p,
    unsigned short* a16, unsigned short* w16x, unsigned short* w16h,
    float* bias, int* lvcnt) {
  size_t tid = (size_t)blockIdx.x * blockDim.x + threadIdx.x;
  size_t nth = (size_t)gridDim.x * blockDim.x;

  const float4* in4 = (const float4*)p.inputs;
  for (size_t i = tid; i < 2097152u; i += nth) {
    float4 v = in4[i];
    ((ushort4*)a16)[i] = make_ushort4(f2bf(v.x), f2bf(v.y), f2bf(v.z), f2bf(v.w));
  }
  for (size_t i = tid; i < 524288u; i += nth) {
    int d = (int)(i >> 18); int r = (int)(i & 262143);
    int cc = r >> 8; int k = r & 255;
    float sx = (cc < 768) ? p.ioux_w[d][cc * 256 + k] : p.fx_w[d][(cc - 768) * 256 + k];
    float sh = (cc < 768) ? p.iouh_w[d][cc * 256 + k] : p.fh_w[d][(cc - 768) * 256 + k];
    w16x[i] = f2bf(sx);
    w16h[i] = f2bf(sh);
  }
  for (size_t i = tid; i < 2048u; i += nth) {
    int d = (int)(i >> 10); int cc = (int)(i & 1023);
    bias[i] = (cc < 768) ? (p.ioux_b[d][cc] + p.iouh_b[d][cc])
                         : (p.fx_b[d][cc - 768] + p.fh_b[d][cc - 768]);
  }
  for (size_t i = tid; i < 2u * NLEV; i += nth) lvcnt[i] = 0;
}

// ---------------------------------------------------------------------------
// levels: per-b tree walks -> dt heights, td depths; children CSR; histograms.
// ---------------------------------------------------------------------------
__global__ __launch_bounds__(256) void levels_kernel(
    const int* __restrict__ parents, int* __restrict__ lev_g,
    int* __restrict__ csr_off, int* __restrict__ csr_dat, int* __restrict__ lvcnt) {
  __shared__ int parL[256], lvdt[256], lvtd[256];
  __shared__ int cmax[257], ccnt[257], coff[257], ccur[257];
  __shared__ int histd[NLEV], histt[NLEV];
  int b = blockIdx.x, t = threadIdx.x;

  parL[t] = parents[t * BB + b];
  for (int v = t; v < 257; v += 256) { cmax[v] = -1; ccnt[v] = 0; }
  if (t < NLEV) { histd[t] = 0; histt[t] = 0; }
  __syncthreads();

  if (t == 0) {
    lvtd[0] = 0;
    for (int i = 1; i < 256; ++i) lvtd[i] = lvtd[parL[i]] + 1;
  }
  if (t == 1) {
    for (int i = 255; i >= 1; --i) {
      int l = cmax[i] + 1;
      lvdt[i] = l;
      int p = parL[i];
      if (cmax[p] < l) cmax[p] = l;
    }
    lvdt[0] = cmax[0] + 1;
  }
  __syncthreads();

  int l1 = min(lvdt[t], NLEV - 1);
  int l2 = min(lvtd[t], NLEV - 1);
  atomicAdd(&histd[l1], 1);
  atomicAdd(&histt[l2], 1);
  if (t >= 1) atomicAdd(&ccnt[parL[t]], 1);
  lev_g[b * 256 + t] = l1;
  lev_g[32768 + b * 256 + t] = l2;
  __syncthreads();

  if (t == 0) {
    int s = 0;
    for (int i = 0; i < 257; ++i) { coff[i] = s; s += ccnt[i]; }
  }
  __syncthreads();
  for (int v = t; v < 257; v += 256) ccur[v] = coff[v];
  __syncthreads();
  if (t >= 1) {
    int pos = atomicAdd(&ccur[parL[t]], 1);
    csr_dat[b * 256 + pos] = t;
  }
  for (int v = t; v < 257; v += 256) csr_off[b * 260 + v] = coff[v];
  if (t < NLEV) {
    if (histd[t]) atomicAdd(&lvcnt[t], histd[t]);
    if (histt[t]) atomicAdd(&lvcnt[NLEV + t], histt[t]);
  }
}

__global__ __launch_bounds__(128) void scan_kernel(const int* __restrict__ lvcnt,
                                                   int* __restrict__ lvoff,
                                                   int* __restrict__ lvcur) {
  __shared__ int c[2 * NLEV], o[2 * (NLEV + 1)];
  int t = threadIdx.x;
  if (t < 2 * NLEV) c[t] = lvcnt[t];
  __syncthreads();
  if (t < 2) {
    int s = 0;
    for (int l = 0; l < NLEV; ++l) { o[t * (NLEV + 1) + l] = s; s += c[t * NLEV + l]; }
    o[t * (NLEV + 1) + NLEV] = s;
  }
  __syncthreads();
  if (t < 2 * (NLEV + 1)) lvoff[t] = o[t];
  if (t < 2 * NLEV) lvcur[t] = o[(t / NLEV) * (NLEV + 1) + (t % NLEV)];
}

__global__ __launch_bounds__(256) void scatter_kernel(const int* __restrict__ lev_g,
    int* __restrict__ lvcur, unsigned* __restrict__ plist) {
  __shared__ int hist[NLEV], base[NLEV], cnt2[NLEV];
  int b = blockIdx.x, d = blockIdx.y, t = threadIdx.x;
  if (t < NLEV) { hist[t] = 0; cnt2[t] = 0; }
  __syncthreads();
  int l = lev_g[d * 32768 + b * 256 + t];
  atomicAdd(&hist[l], 1);
  __syncthreads();
  if (t < NLEV && hist[t] > 0) base[t] = atomicAdd(&lvcur[d * NLEV + t], hist[t]);
  __syncthreads();
  int r = atomicAdd(&cnt2[l], 1);
  plist[d * 32768 + base[l] + r] = ((unsigned)b << 16) | (unsigned)t;
}

// ---------------------------------------------------------------------------
// xproj GEMM, tiled: 128x128 tile, BK=64, LDS-staged. Grid (256, 16).
// ---------------------------------------------------------------------------
__global__ __launch_bounds__(256) void xproj_gemm(
    const unsigned short* __restrict__ a16,
    const unsigned short* __restrict__ w16x,
    unsigned short* __restrict__ xp) {
  __shared__ unsigned short As[128 * 72], Bs[128 * 72];
  int t = threadIdx.x;
  int w = t >> 6, lane = t & 63, l16 = lane & 15, quad = lane >> 4;
  int m0 = blockIdx.x * 128;
  int d = blockIdx.y >> 3;
  int cc0 = (blockIdx.y & 7) * 128;
  const unsigned short* Bg = w16x + ((size_t)d * 1024 + cc0) * 256;
  int lr = t >> 3, seg = t & 7;

  floatx4 acc[4][4];
#pragma unroll
  for (int i = 0; i < 4; ++i)
#pragma unroll
    for (int j = 0; j < 4; ++j) acc[i][j] = (floatx4){0.f, 0.f, 0.f, 0.f};

  for (int ck = 0; ck < 4; ++ck) {
    int k0 = ck * 64;
#pragma unroll
    for (int it = 0; it < 4; ++it) {
      int row = it * 32 + lr;
      *(uint4*)&As[row * 72 + seg * 8] =
          *(const uint4*)(a16 + (size_t)(m0 + row) * 256 + k0 + seg * 8);
      *(uint4*)&Bs[row * 72 + seg * 8] =
          *(const uint4*)(Bg + (size_t)row * 256 + k0 + seg * 8);
    }
    __syncthreads();
#pragma unroll
    for (int kc = 0; kc < 2; ++kc) {
      int kg = kc * 4 + quad;
      short8 af[4], bf[4];
#pragma unroll
      for (int mf = 0; mf < 4; ++mf)
        af[mf] = *(const short8*)&As[((w & 1) * 64 + mf * 16 + l16) * 72 + kg * 8];
#pragma unroll
      for (int nf = 0; nf < 4; ++nf)
        bf[nf] = *(const short8*)&Bs[((w >> 1) * 64 + nf * 16 + l16) * 72 + kg * 8];
#pragma unroll
      for (int mf = 0; mf < 4; ++mf)
#pragma unroll
        for (int nf = 0; nf < 4; ++nf)
          acc[mf][nf] = __builtin_amdgcn_mfma_f32_16x16x32_bf16(af[mf], bf[nf], acc[mf][nf], 0, 0, 0);
    }
    __syncthreads();
  }
  unsigned short* out = xp + (size_t)d * 33554432u;
#pragma unroll
  for (int mf = 0; mf < 4; ++mf)
#pragma unroll
    for (int nf = 0; nf < 4; ++nf)
#pragma unroll
      for (int r = 0; r < 4; ++r) {
        int row = m0 + (w & 1) * 64 + mf * 16 + quad * 4 + r;
        int col = cc0 + (w >> 1) * 64 + nf * 16 + l16;
        out[(size_t)row * 1024 + col] = f2bf(acc[mf][nf][r]);
      }
}

// ---------------------------------------------------------------------------
// gather (fallback path): per pair of level l, build bf16 A-row.
// ---------------------------------------------------------------------------
__global__ __launch_bounds__(256) void gather_kernel(int l,
    const int* __restrict__ lvoff, const unsigned* __restrict__ plist,
    const int* __restrict__ csr_off, const int* __restrict__ csr_dat,
    const int* __restrict__ parents, const float* __restrict__ hidd,
    unsigned short* __restrict__ A16ws) {
  int d = blockIdx.z;
  int i0 = lvoff[d * (NLEV + 1) + l];
  int i1 = lvoff[d * (NLEV + 1) + l + 1];
  int wv = threadIdx.x >> 6, lane = threadIdx.x & 63;
  for (int gi = i0 + blockIdx.x * 4 + wv; gi < i1; gi += 512) {
    unsigned pr = plist[d * 32768 + gi];
    int b = pr >> 16, node = pr & 0xffff;
    float sx = 0.f, sy = 0.f, sz = 0.f, sw = 0.f;
    if (d == 0) {
      int o0 = csr_off[b * 260 + node], o1 = csr_off[b * 260 + node + 1];
      for (int e = o0; e < o1; ++e) {
        int cn = csr_dat[b * 256 + e];
        float4 v = *(const float4*)(hidd + ((size_t)cn * BB + b) * 512 + lane * 4);
        sx += v.x; sy += v.y; sz += v.z; sw += v.w;
      }
    } else {
      int par = parents[node * BB + b];
      if (par != LL) {
        float4 v = *(const float4*)(hidd + ((size_t)par * BB + b) * 512 + 256 + lane * 4);
        sx = v.x; sy = v.y; sz = v.z; sw = v.w;
      }
    }
    *(ushort4*)&A16ws[(size_t)d * 8388608u + (size_t)gi * 256 + lane * 4] =
        make_ushort4(f2bf(sx), f2bf(sy), f2bf(sz), f2bf(sw));
  }
}

// ---------------------------------------------------------------------------
// level GEMM (fallback path): identical math to fused phase 2.
// ---------------------------------------------------------------------------
__global__ __launch_bounds__(256) void level_gemm(int l,
    const unsigned short* __restrict__ w16h, const float* __restrict__ bias,
    const unsigned short* __restrict__ xp,
    const int* __restrict__ lvoff, const unsigned* __restrict__ plist,
    const int* __restrict__ csr_off, const int* __restrict__ csr_dat,
    const int* __restrict__ parents, const unsigned short* __restrict__ A16ws,
    float* __restrict__ cells, float* __restrict__ hidd) {
  __shared__ unsigned short As[128 * 72], Bs[128 * 72];
  int d = blockIdx.z;
  int i0 = lvoff[d * (NLEV + 1) + l];
  int i1 = lvoff[d * (NLEV + 1) + l + 1];
  int np = i1 - i0;
  if (np <= 0) return;
  int ntiles = (np + 127) >> 7;

  int t = threadIdx.x;
  int w = t >> 6, lane = t & 63, l16 = lane & 15, quad = lane >> 4;
  int j0 = blockIdx.y * 32;
  const unsigned short* Bg = w16h + (size_t)d * 262144u;
  const unsigned short* Ag = A16ws + (size_t)d * 8388608u;
  int lr = t >> 3, seg = t & 7;

  for (int mt = blockIdx.x; mt < ntiles; mt += gridDim.x) {
    floatx4 acc[2][4][2];
#pragma unroll
    for (int mf = 0; mf < 2; ++mf)
#pragma unroll
      for (int g = 0; g < 4; ++g)
#pragma unroll
        for (int js = 0; js < 2; ++js) acc[mf][g][js] = (floatx4){0.f, 0.f, 0.f, 0.f};

    for (int ck = 0; ck < 4; ++ck) {
      int k0 = ck * 64;
#pragma unroll
      for (int it = 0; it < 4; ++it) {
        int row = it * 32 + lr;
        int gi = i0 + mt * 128 + row;
        uint4 av = make_uint4(0u, 0u, 0u, 0u);
        if (gi < i1) av = *(const uint4*)(Ag + (size_t)gi * 256 + k0 + seg * 8);
        *(uint4*)&As[row * 72 + seg * 8] = av;
        int cc = ((row >> 5) << 8) + j0 + (row & 31);
        *(uint4*)&Bs[row * 72 + seg * 8] =
            *(const uint4*)(Bg + (size_t)cc * 256 + k0 + seg * 8);
      }
      __syncthreads();
#pragma unroll
      for (int kc = 0; kc < 2; ++kc) {
        int kg = kc * 4 + quad;
        short8 af[2];
#pragma unroll
        for (int mf = 0; mf < 2; ++mf)
          af[mf] = *(const short8*)&As[(w * 32 + mf * 16 + l16) * 72 + kg * 8];
#pragma unroll
        for (int g = 0; g < 4; ++g)
#pragma unroll
          for (int js = 0; js < 2; ++js) {
            short8 bf = *(const short8*)&Bs[(g * 32 + js * 16 + l16) * 72 + kg * 8];
            acc[0][g][js] = __builtin_amdgcn_mfma_f32_16x16x32_bf16(af[0], bf, acc[0][g][js], 0, 0, 0);
            acc[1][g][js] = __builtin_amdgcn_mfma_f32_16x16x32_bf16(af[1], bf, acc[1][g][js], 0, 0, 0);
          }
      }
      __syncthreads();
    }

#pragma unroll
    for (int mf = 0; mf < 2; ++mf)
#pragma unroll
      for (int r = 0; r < 4; ++r) {
        int row = w * 32 + mf * 16 + quad * 4 + r;
        int gi = i0 + mt * 128 + row;
        if (gi >= i1) continue;
        unsigned pr = plist[d * 32768 + gi];
        int b = pr >> 16, node = pr & 0xffff;
        float sc0 = 0.f, sc1 = 0.f;
        if (d == 0) {
          int o0 = csr_off[b * 260 + node], o1 = csr_off[b * 260 + node + 1];
          for (int e = o0; e < o1; ++e) {
            int cn = csr_dat[b * 256 + e];
            const float* cbase = cells + ((size_t)cn * BB + b) * 512;
            sc0 += cbase[j0 + l16];
            sc1 += cbase[j0 + 16 + l16];
          }
        } else {
          int par = parents[node * BB + b];
          if (par != LL) {
            const float* cbase = cells + ((size_t)par * BB + b) * 512 + 256;
            sc0 = cbase[j0 + l16];
            sc1 = cbase[j0 + 16 + l16];
          }
        }
        const unsigned short* xrow = xp + (size_t)d * 33554432u + ((size_t)node * BB + b) * 1024;
        const float* brow = bias + d * 1024;
#pragma unroll
        for (int js = 0; js < 2; ++js) {
          int j = j0 + js * 16 + l16;
          float sc = js ? sc1 : sc0;
          float pi = acc[mf][0][js][r] + brow[j]       + bf2f(xrow[j]);
          float po = acc[mf][1][js][r] + brow[256 + j] + bf2f(xrow[256 + j]);
          float pu = acc[mf][2][js][r] + brow[512 + j] + bf2f(xrow[512 + j]);
          float pf = acc[mf][3][js][r] + brow[768 + j] + bf2f(xrow[768 + j]);
          float gi_ = sigm(pi), go = sigm(po), gu = tanh_(pu), gf = sigm(pf);
          float c = gi_ * gu + gf * sc;
          float h = go * tanh_(c);
          size_t ob = ((size_t)node * BB + b) * 512 + (d << 8) + j;
          cells[ob] = c;
          hidd[ob] = h;
        }
      }
  }
}

// ---------------------------------------------------------------------------
// fused level loop: ONE cooperative kernel, grid (16,8,2) = 256 blocks
// (<= 1 block/CU, guaranteed co-resident; round-3's 512 likely exceeded the
// runtime's co-residency bound and the launch was rejected -> zero output).
// Per level: phase 1 gather -> fence+sync+fence -> phase 2 GEMM+gating ->
// fence+sync+fence.
// ---------------------------------------------------------------------------
struct FusedArgs {
  const unsigned short* w16h; const float* bias; const unsigned short* xp;
  const int* lvoff; const unsigned* plist;
  const int* csr_off; const int* csr_dat; const int* parents;
  unsigned short* A16ws; float* cells; float* hidd;
};

__global__ __launch_bounds__(256, 2) void levels_fused(FusedArgs a) {
  __shared__ unsigned short As[128 * 72], Bs[128 * 72];
  cg::grid_group grid = cg::this_grid();

  int t = threadIdx.x;
  int w = t >> 6, lane = t & 63, l16 = lane & 15, quad = lane >> 4;
  int d = blockIdx.z;
  int gblk = (int)blockIdx.x + (int)blockIdx.y * (int)gridDim.x;  // gather block id
  int nglb = (int)gridDim.x * (int)gridDim.y;                     // per-direction blocks
  int j0 = blockIdx.y * 32;
  int lr = t >> 3, seg = t & 7;
  const unsigned short* Bg = a.w16h + (size_t)d * 262144u;
  const unsigned short* Ag = a.A16ws + (size_t)d * 8388608u;
  unsigned short* Aw = a.A16ws + (size_t)d * 8388608u;

  for (int l = 0; l < NLEV; ++l) {
    int i0d = a.lvoff[l], i1d = a.lvoff[l + 1];
    int i0t = a.lvoff[(NLEV + 1) + l], i1t = a.lvoff[(NLEV + 1) + l + 1];
    if (i1d == i0d && i1t == i0t) continue;   // uniform: past max level, no syncs
    int i0 = d ? i0t : i0d, i1 = d ? i1t : i1d;
    int np = i1 - i0;

    // ---- phase 1: gather A rows (1 wave per pair) ----
    for (int gi = i0 + gblk * 4 + w; gi < i1; gi += nglb * 4) {
      unsigned pr = a.plist[d * 32768 + gi];
      int b = pr >> 16, node = pr & 0xffff;
      float sx = 0.f, sy = 0.f, sz = 0.f, sw = 0.f;
      if (d == 0) {
        int o0 = a.csr_off[b * 260 + node], o1 = a.csr_off[b * 260 + node + 1];
        for (int e = o0; e < o1; ++e) {
          int cn = a.csr_dat[b * 256 + e];
          float4 v = *(const float4*)(a.hidd + ((size_t)cn * BB + b) * 512 + lane * 4);
          sx += v.x; sy += v.y; sz += v.z; sw += v.w;
        }
      } else {
        int par = a.parents[node * BB + b];
        if (par != LL) {
          float4 v = *(const float4*)(a.hidd + ((size_t)par * BB + b) * 512 + 256 + lane * 4);
          sx = v.x; sy = v.y; sz = v.z; sw = v.w;
        }
      }
      *(ushort4*)&Aw[(size_t)gi * 256 + lane * 4] =
          make_ushort4(f2bf(sx), f2bf(sy), f2bf(sz), f2bf(sw));
    }
    DEV_FENCE();
    grid.sync();
    DEV_FENCE();

    // ---- phase 2: level GEMM + fused gating epilogue ----
    if (np > 0) {
      int ntiles = (np + 127) >> 7;
      for (int mt = blockIdx.x; mt < ntiles; mt += gridDim.x) {
        floatx4 acc[2][4][2];
#pragma unroll
        for (int mf = 0; mf < 2; ++mf)
#pragma unroll
          for (int g = 0; g < 4; ++g)
#pragma unroll
            for (int js = 0; js < 2; ++js) acc[mf][g][js] = (floatx4){0.f, 0.f, 0.f, 0.f};

        for (int ck = 0; ck < 4; ++ck) {
          int k0 = ck * 64;
#pragma unroll
          for (int it = 0; it < 4; ++it) {
            int row = it * 32 + lr;
            int gi = i0 + mt * 128 + row;
            uint4 av = make_uint4(0u, 0u, 0u, 0u);
            if (gi < i1) av = *(const uint4*)(Ag + (size_t)gi * 256 + k0 + seg * 8);
            *(uint4*)&As[row * 72 + seg * 8] = av;
            int cc = ((row >> 5) << 8) + j0 + (row & 31);
            *(uint4*)&Bs[row * 72 + seg * 8] =
                *(const uint4*)(Bg + (size_t)cc * 256 + k0 + seg * 8);
          }
          __syncthreads();
#pragma unroll
          for (int kc = 0; kc < 2; ++kc) {
            int kg = kc * 4 + quad;
            short8 af[2];
#pragma unroll
            for (int mf = 0; mf < 2; ++mf)
              af[mf] = *(const short8*)&As[(w * 32 + mf * 16 + l16) * 72 + kg * 8];
#pragma unroll
            for (int g = 0; g < 4; ++g)
#pragma unroll
              for (int js = 0; js < 2; ++js) {
                short8 bf = *(const short8*)&Bs[(g * 32 + js * 16 + l16) * 72 + kg * 8];
                acc[0][g][js] = __builtin_amdgcn_mfma_f32_16x16x32_bf16(af[0], bf, acc[0][g][js], 0, 0, 0);
                acc[1][g][js] = __builtin_amdgcn_mfma_f32_16x16x32_bf16(af[1], bf, acc[1][g][js], 0, 0, 0);
              }
          }
          __syncthreads();
        }

#pragma unroll
        for (int mf = 0; mf < 2; ++mf)
#pragma unroll
          for (int r = 0; r < 4; ++r) {
            int row = w * 32 + mf * 16 + quad * 4 + r;
            int gi = i0 + mt * 128 + row;
            if (gi >= i1) continue;
            unsigned pr = a.plist[d * 32768 + gi];
            int b = pr >> 16, node = pr & 0xffff;
            float sc0 = 0.f, sc1 = 0.f;
            if (d == 0) {
              int o0 = a.csr_off[b * 260 + node], o1 = a.csr_off[b * 260 + node + 1];
              for (int e = o0; e < o1; ++e) {
                int cn = a.csr_dat[b * 256 + e];
                const float* cbase = a.cells + ((size_t)cn * BB + b) * 512;
                sc0 += cbase[j0 + l16];
                sc1 += cbase[j0 + 16 + l16];
              }
            } else {
              int par = a.parents[node * BB + b];
              if (par != LL) {
                const float* cbase = a.cells + ((size_t)par * BB + b) * 512 + 256;
                sc0 = cbase[j0 + l16];
                sc1 = cbase[j0 + 16 + l16];
              }
            }
            const unsigned short* xrow = a.xp + (size_t)d * 33554432u + ((size_t)node * BB + b) * 1024;
            const float* brow = a.bias + d * 1024;
#pragma unroll
            for (int js = 0; js < 2; ++js) {
              int j = j0 + js * 16 + l16;
              float sc = js ? sc1 : sc0;
              float pi = acc[mf][0][js][r] + brow[j]       + bf2f(xrow[j]);
              float po = acc[mf][1][js][r] + brow[256 + j] + bf2f(xrow[256 + j]);
              float pu = acc[mf][2][js][r] + brow[512 + j] + bf2f(xrow[512 + j]);
              float pf = acc[mf][3][js][r] + brow[768 + j] + bf2f(xrow[768 + j]);
              float gi_ = sigm(pi), go = sigm(po), gu = tanh_(pu), gf = sigm(pf);
              float c = gi_ * gu + gf * sc;
              float h = go * tanh_(c);
              size_t ob = ((size_t)node * BB + b) * 512 + (d << 8) + j;
              a.cells[ob] = c;
              a.hidd[ob] = h;
            }
          }
      }
    }
    DEV_FENCE();
    grid.sync();
    DEV_FENCE();
  }
}

// ---------------------------------------------------------------------------
extern "C" void kernel_launch(void* const* d_in, const int* in_sizes, int n_in,
                              void* d_out, int out_size, void* d_ws, size_t ws_size,
                              hipStream_t stream) {
  Params p;
  p.inputs = (const float*)d_in[0];
  const int* parents = (const int*)d_in[2];
  for (int d = 0; d < 2; ++d) {
    int o = 3 + d * 8;
    p.ioux_w[d] = (const float*)d_in[o + 0];
    p.ioux_b[d] = (const float*)d_in[o + 1];
    p.iouh_w[d] = (const float*)d_in[o + 2];
    p.iouh_b[d] = (const float*)d_in[o + 3];
    p.fx_w[d]   = (const float*)d_in[o + 4];
    p.fx_b[d]   = (const float*)d_in[o + 5];
    p.fh_w[d]   = (const float*)d_in[o + 6];
    p.fh_b[d]   = (const float*)d_in[o + 7];
  }

  unsigned short* a16   = (unsigned short*)d_ws;        // 8,388,608 u16
  unsigned short* w16x  = a16 + 8388608u;               // 524,288
  unsigned short* w16h  = w16x + 524288u;               // 524,288
  unsigned short* xp    = w16h + 524288u;               // 67,108,864
  unsigned short* A16ws = xp + 67108864u;               // 16,777,216
  float* bias = (float*)(A16ws + 16777216u);            // 2048 f32
  int*   lev_g   = (int*)(bias + 2048u);                // 65,536
  int*   csr_off = lev_g + 65536;                       // 33,280
  int*   csr_dat = csr_off + 33280;                     // 32,768
  int*   lvcnt   = csr_dat + 32768;                     // 96
  int*   lvoff   = lvcnt + 2 * NLEV;                    // 98
  int*   lvcur   = lvoff + 2 * (NLEV + 1);              // 96
  unsigned* plist = (unsigned*)(lvcur + 2 * NLEV);      // 65,536

  float* cells = (float*)d_out;                         // [256][128][512]
  float* hidd  = cells + 16777216u;

  prep_kernel<<<dim3(1024), dim3(256), 0, stream>>>(p, a16, w16x, w16h, bias, lvcnt);
  levels_kernel<<<dim3(128), dim3(256), 0, stream>>>(parents, lev_g, csr_off, csr_dat, lvcnt);
  scan_kernel<<<dim3(1), dim3(128), 0, stream>>>(lvcnt, lvoff, lvcur);
  scatter_kernel<<<dim3(128, 2), dim3(256), 0, stream>>>(lev_g, lvcur, plist);
  xproj_gemm<<<dim3(256, 16), dim3(256), 0, stream>>>(a16, w16x, xp);

  FusedArgs fa;
  fa.w16h = w16h; fa.bias = bias; fa.xp = xp;
  fa.lvoff = lvoff; fa.plist = plist;
  fa.csr_off = csr_off; fa.csr_dat = csr_dat; fa.parents = parents;
  fa.A16ws = A16ws; fa.cells = cells; fa.hidd = hidd;
  void* kargs[] = { &fa };
  hipError_t cerr = hipLaunchCooperativeKernel((void*)levels_fused, dim3(16, 8, 2),
                                               dim3(256), kargs, 0, stream);
  if (cerr != hipSuccess) {
    // Fallback: known-good per-level launch chain (baseline path).
    for (int l = 0; l < NLEV; ++l) {
      gather_kernel<<<dim3(128, 1, 2), dim3(256), 0, stream>>>(l, lvoff, plist,
          csr_off, csr_dat, parents, hidd, A16ws);
      level_gemm<<<dim3(32, 8, 2), dim3(256), 0, stream>>>(l, w16h, bias, xp,
          lvoff, plist, csr_off, csr_dat, parents, A16ws, cells, hidd);
    }
  }
}

// Round 9
// 1740.437 us; speedup vs baseline: 1.7985x; 1.7985x over previous
//
#include <hip/hip_runtime.h>

#define LL 256
#define BB 128
#define NLEV 48

typedef float  floatx4 __attribute__((ext_vector_type(4)));
typedef short  short8  __attribute__((ext_vector_type(8)));

struct Params {
  const float* inputs;
  const float* ioux_w[2]; const float* ioux_b[2];
  const float* iouh_w[2]; const float* iouh_b[2];
  const float* fx_w[2];   const float* fx_b[2];
  const float* fh_w[2];   const float* fh_b[2];
};

__device__ __forceinline__ unsigned short f2bf(float f) {
  unsigned u = __float_as_uint(f);
  u += 0x7fffu + ((u >> 16) & 1u);
  return (unsigned short)(u >> 16);
}
__device__ __forceinline__ float bf2f(unsigned u) { return __uint_as_float(u << 16); }
__device__ __forceinline__ float sigm(float x) { return 1.0f / (1.0f + __expf(-x)); }
__device__ __forceinline__ float tanh_(float x) { return 1.0f - 2.0f / (1.0f + __expf(2.0f * x)); }

// ---------------------------------------------------------------------------
// prep: bf16 inputs; w16x in row-major gate-planar rows (for xproj GEMM);
// w16h in MFMA B-FRAGMENT layout: value(d, cc, k) stored at
//   [((d*64 + nf)*8 + ks)*512 + lane*8 + e]
// where nf=cc>>4, lane=(k&31)>>3)*16 + (cc&15), ks=k>>5, e=k&7 — so one
// wave's B-fragment for (nf, ks) is a single contiguous, coalesced 1KB load.
// Folded bias[d][1024]; lvcnt zeroed (used by levels_kernel atomics).
// ---------------------------------------------------------------------------
__global__ __launch_bounds__(256) void prep_kernel(Params p,
    unsigned short* a16, unsigned short* w16x, unsigned short* w16h,
    float* bias, int* lvcnt) {
  size_t tid = (size_t)blockIdx.x * blockDim.x + threadIdx.x;
  size_t nth = (size_t)gridDim.x * blockDim.x;

  const float4* in4 = (const float4*)p.inputs;
  for (size_t i = tid; i < 2097152u; i += nth) {
    float4 v = in4[i];
    ((ushort4*)a16)[i] = make_ushort4(f2bf(v.x), f2bf(v.y), f2bf(v.z), f2bf(v.w));
  }
  for (size_t i = tid; i < 524288u; i += nth) {
    int d = (int)(i >> 18); int r = (int)(i & 262143);
    int cc = r >> 8; int k = r & 255;
    float sx = (cc < 768) ? p.ioux_w[d][cc * 256 + k] : p.fx_w[d][(cc - 768) * 256 + k];
    float sh = (cc < 768) ? p.iouh_w[d][cc * 256 + k] : p.fh_w[d][(cc - 768) * 256 + k];
    w16x[i] = f2bf(sx);
    int nf = cc >> 4, lcc = cc & 15;
    int ks = k >> 5, kr = k & 31;
    int lane = (kr >> 3) * 16 + lcc, e = kr & 7;
    w16h[((size_t)(d * 64 + nf) * 8 + ks) * 512 + lane * 8 + e] = f2bf(sh);
  }
  for (size_t i = tid; i < 2048u; i += nth) {
    int d = (int)(i >> 10); int cc = (int)(i & 1023);
    bias[i] = (cc < 768) ? (p.ioux_b[d][cc] + p.iouh_b[d][cc])
                         : (p.fx_b[d][cc - 768] + p.fh_b[d][cc - 768]);
  }
  for (size_t i = tid; i < 2u * NLEV; i += nth) lvcnt[i] = 0;
}

// ---------------------------------------------------------------------------
// levels: per-b tree walks -> dt heights, td depths; children CSR.
// ---------------------------------------------------------------------------
__global__ __launch_bounds__(256) void levels_kernel(
    const int* __restrict__ parents, int* __restrict__ lev_g,
    int* __restrict__ csr_off, int* __restrict__ csr_dat, int* __restrict__ lvcnt) {
  __shared__ int parL[256], lvdt[256], lvtd[256];
  __shared__ int cmax[257], ccnt[257], coff[257], ccur[257];
  int b = blockIdx.x, t = threadIdx.x;

  parL[t] = parents[t * BB + b];
  for (int v = t; v < 257; v += 256) { cmax[v] = -1; ccnt[v] = 0; }
  __syncthreads();

  if (t == 0) {
    lvtd[0] = 0;
    for (int i = 1; i < 256; ++i) lvtd[i] = lvtd[parL[i]] + 1;
  }
  if (t == 1) {
    for (int i = 255; i >= 1; --i) {
      int l = cmax[i] + 1;
      lvdt[i] = l;
      int p = parL[i];
      if (cmax[p] < l) cmax[p] = l;
    }
    lvdt[0] = cmax[0] + 1;
  }
  __syncthreads();

  int l1 = min(lvdt[t], NLEV - 1);
  int l2 = min(lvtd[t], NLEV - 1);
  if (t >= 1) atomicAdd(&ccnt[parL[t]], 1);
  lev_g[b * 256 + t] = l1;
  lev_g[32768 + b * 256 + t] = l2;
  __syncthreads();

  if (t == 0) {
    int s = 0;
    for (int i = 0; i < 257; ++i) { coff[i] = s; s += ccnt[i]; }
  }
  __syncthreads();
  for (int v = t; v < 257; v += 256) ccur[v] = coff[v];
  __syncthreads();
  if (t >= 1) {
    int pos = atomicAdd(&ccur[parL[t]], 1);
    csr_dat[b * 256 + pos] = t;
  }
  for (int v = t; v < 257; v += 256) csr_off[b * 260 + v] = coff[v];
}

// ---------------------------------------------------------------------------
// xproj GEMM, tiled: 128x128 tile, BK=64, LDS-staged. Grid (256, 16).
// ---------------------------------------------------------------------------
__global__ __launch_bounds__(256) void xproj_gemm(
    const unsigned short* __restrict__ a16,
    const unsigned short* __restrict__ w16x,
    unsigned short* __restrict__ xp) {
  __shared__ unsigned short As[128 * 72], Bs[128 * 72];
  int t = threadIdx.x;
  int w = t >> 6, lane = t & 63, l16 = lane & 15, quad = lane >> 4;
  int m0 = blockIdx.x * 128;
  int d = blockIdx.y >> 3;
  int cc0 = (blockIdx.y & 7) * 128;
  const unsigned short* Bg = w16x + ((size_t)d * 1024 + cc0) * 256;
  int lr = t >> 3, seg = t & 7;

  floatx4 acc[4][4];
#pragma unroll
  for (int i = 0; i < 4; ++i)
#pragma unroll
    for (int j = 0; j < 4; ++j) acc[i][j] = (floatx4){0.f, 0.f, 0.f, 0.f};

  for (int ck = 0; ck < 4; ++ck) {
    int k0 = ck * 64;
#pragma unroll
    for (int it = 0; it < 4; ++it) {
      int row = it * 32 + lr;
      *(uint4*)&As[row * 72 + seg * 8] =
          *(const uint4*)(a16 + (size_t)(m0 + row) * 256 + k0 + seg * 8);
      *(uint4*)&Bs[row * 72 + seg * 8] =
          *(const uint4*)(Bg + (size_t)row * 256 + k0 + seg * 8);
    }
    __syncthreads();
#pragma unroll
    for (int kc = 0; kc < 2; ++kc) {
      int kg = kc * 4 + quad;
      short8 af[4], bf[4];
#pragma unroll
      for (int mf = 0; mf < 4; ++mf)
        af[mf] = *(const short8*)&As[((w & 1) * 64 + mf * 16 + l16) * 72 + kg * 8];
#pragma unroll
      for (int nf = 0; nf < 4; ++nf)
        bf[nf] = *(const short8*)&Bs[((w >> 1) * 64 + nf * 16 + l16) * 72 + kg * 8];
#pragma unroll
      for (int mf = 0; mf < 4; ++mf)
#pragma unroll
        for (int nf = 0; nf < 4; ++nf)
          acc[mf][nf] = __builtin_amdgcn_mfma_f32_16x16x32_bf16(af[mf], bf[nf], acc[mf][nf], 0, 0, 0);
    }
    __syncthreads();
  }
  unsigned short* out = xp + (size_t)d * 33554432u;
#pragma unroll
  for (int mf = 0; mf < 4; ++mf)
#pragma unroll
    for (int nf = 0; nf < 4; ++nf)
#pragma unroll
      for (int r = 0; r < 4; ++r) {
        int row = m0 + (w & 1) * 64 + mf * 16 + quad * 4 + r;
        int col = cc0 + (w >> 1) * 64 + nf * 16 + l16;
        out[(size_t)row * 1024 + col] = f2bf(acc[mf][nf][r]);
      }
}

// ---------------------------------------------------------------------------
// tree_fused: ONE block per (b, d) chain — grid (128, 2), 256 thr, 1 blk/CU.
// The 256 chains are fully independent (node (b,n) only reads same-b state),
// so NO grid sync / fences are needed: a block's own global writes are
// visible to itself (same CU) across __syncthreads().
// Per level, M-tiles of 32 nodes: gather A rows (sum children h / parent h)
// into LDS bf16, MFMA against fragment-swizzled W_h read straight from L2
// (contiguous 1KB per B-fragment), fused gating epilogue.
// Wave w owns j-range [w*64, w*64+64): nf = g*16 + w*4 + jj  (all 4 gates
// for a j-column live in the same lane -> gating is lane-local).
// ---------------------------------------------------------------------------
__global__ __launch_bounds__(256, 1) void tree_fused(
    const int* __restrict__ lev_g, const int* __restrict__ csr_off_g,
    const int* __restrict__ csr_dat_g, const int* __restrict__ parents,
    const unsigned short* __restrict__ w16hf, const float* __restrict__ bias,
    const unsigned short* __restrict__ xp,
    float* __restrict__ cells, float* __restrict__ hidd) {
  __shared__ unsigned short As[32 * 264];
  __shared__ int lvl[256], ord[256], parL[256], cdat[256];
  __shared__ int coff[257];
  __shared__ int hist[NLEV], loff[NLEV + 1], cur[NLEV];

  int b = blockIdx.x, d = blockIdx.y, t = threadIdx.x;
  int w = t >> 6, lane = t & 63, l16 = lane & 15, quad = lane >> 4;
  int gr = t >> 3, gs = t & 7;   // gather: row 0..31, k-segment 0..7

  lvl[t]  = lev_g[d * 32768 + b * 256 + t];
  parL[t] = parents[t * BB + b];
  cdat[t] = csr_dat_g[b * 256 + t];
  for (int v = t; v < 257; v += 256) coff[v] = csr_off_g[b * 260 + v];
  if (t < NLEV) hist[t] = 0;
  __syncthreads();
  atomicAdd(&hist[lvl[t]], 1);
  __syncthreads();
  if (t == 0) {
    int s = 0;
    for (int l = 0; l < NLEV; ++l) { loff[l] = s; s += hist[l]; }
    loff[NLEV] = s;
  }
  __syncthreads();
  if (t < NLEV) cur[t] = loff[t];
  __syncthreads();
  { int pos = atomicAdd(&cur[lvl[t]], 1); ord[pos] = t; }
  __syncthreads();

  const float* brow = bias + d * 1024;
  const unsigned short* Wf = w16hf + (size_t)d * 262144u;
  const unsigned short* xpd = xp + (size_t)d * 33554432u;

  for (int l = 0; l < NLEV; ++l) {
    int n0 = loff[l], np = loff[l + 1] - n0;
    if (np == 0) continue;
    int ntiles = (np + 31) >> 5;
    for (int mt = 0; mt < ntiles; ++mt) {
      // ---- gather A rows: sum children h (dt) / parent h (td) -> bf16 LDS
      {
        int i = mt * 32 + gr;
        if (i < np) {
          float a8[32];
#pragma unroll
          for (int q = 0; q < 32; ++q) a8[q] = 0.f;
          int node = ord[n0 + i];
          if (d == 0) {
            int o0 = coff[node], o1 = coff[node + 1];
            for (int e = o0; e < o1; ++e) {
              const float4* hb = (const float4*)(hidd +
                  ((size_t)cdat[e] * BB + b) * 512 + gs * 32);
#pragma unroll
              for (int q = 0; q < 8; ++q) {
                float4 v = hb[q];
                a8[q*4+0] += v.x; a8[q*4+1] += v.y; a8[q*4+2] += v.z; a8[q*4+3] += v.w;
              }
            }
          } else {
            int par = parL[node];
            if (par != LL) {
              const float4* hb = (const float4*)(hidd +
                  ((size_t)par * BB + b) * 512 + 256 + gs * 32);
#pragma unroll
              for (int q = 0; q < 8; ++q) {
                float4 v = hb[q];
                a8[q*4+0] = v.x; a8[q*4+1] = v.y; a8[q*4+2] = v.z; a8[q*4+3] = v.w;
              }
            }
          }
#pragma unroll
          for (int q = 0; q < 4; ++q) {
            short8 o;
#pragma unroll
            for (int e = 0; e < 8; ++e) o[e] = (short)f2bf(a8[q * 8 + e]);
            *(short8*)&As[gr * 264 + gs * 32 + q * 8] = o;
          }
        }
      }
      __syncthreads();

      // ---- MFMA: A from LDS, B fragments straight from L2 (1KB coalesced)
      short8 a[2][8];
#pragma unroll
      for (int mf = 0; mf < 2; ++mf)
#pragma unroll
        for (int ks = 0; ks < 8; ++ks)
          a[mf][ks] = *(const short8*)&As[(mf * 16 + l16) * 264 + ks * 32 + quad * 8];
      floatx4 acc[2][4][4];
#pragma unroll
      for (int mf = 0; mf < 2; ++mf)
#pragma unroll
        for (int g = 0; g < 4; ++g)
#pragma unroll
          for (int jj = 0; jj < 4; ++jj) acc[mf][g][jj] = (floatx4){0.f, 0.f, 0.f, 0.f};
#pragma unroll
      for (int ks = 0; ks < 8; ++ks)
#pragma unroll
        for (int g = 0; g < 4; ++g)
#pragma unroll
          for (int jj = 0; jj < 4; ++jj) {
            int nf = g * 16 + w * 4 + jj;
            short8 bf = *(const short8*)(Wf + ((size_t)(nf * 8 + ks) * 64 + lane) * 8);
            acc[0][g][jj] = __builtin_amdgcn_mfma_f32_16x16x32_bf16(a[0][ks], bf, acc[0][g][jj], 0, 0, 0);
            acc[1][g][jj] = __builtin_amdgcn_mfma_f32_16x16x32_bf16(a[1][ks], bf, acc[1][g][jj], 0, 0, 0);
          }
      __syncthreads();

      // ---- epilogue: bias + xproj + gating; sc gathered lane-local
#pragma unroll
      for (int mf = 0; mf < 2; ++mf)
#pragma unroll
        for (int r = 0; r < 4; ++r) {
          int i = mt * 32 + mf * 16 + quad * 4 + r;
          if (i >= np) continue;
          int node = ord[n0 + i];
          float scv[4] = {0.f, 0.f, 0.f, 0.f};
          int jb = w * 64 + l16;
          if (d == 0) {
            int o0 = coff[node], o1 = coff[node + 1];
            for (int e = o0; e < o1; ++e) {
              const float* cb = cells + ((size_t)cdat[e] * BB + b) * 512;
              scv[0] += cb[jb];      scv[1] += cb[jb + 16];
              scv[2] += cb[jb + 32]; scv[3] += cb[jb + 48];
            }
          } else {
            int par = parL[node];
            if (par != LL) {
              const float* cb = cells + ((size_t)par * BB + b) * 512 + 256;
              scv[0] = cb[jb];      scv[1] = cb[jb + 16];
              scv[2] = cb[jb + 32]; scv[3] = cb[jb + 48];
            }
          }
          const unsigned short* xr = xpd + ((size_t)node * BB + b) * 1024;
          size_t ob = ((size_t)node * BB + b) * 512 + (d << 8);
#pragma unroll
          for (int jj = 0; jj < 4; ++jj) {
            int j = w * 64 + jj * 16 + l16;
            float pi = acc[mf][0][jj][r] + brow[j]       + bf2f(xr[j]);
            float po = acc[mf][1][jj][r] + brow[256 + j] + bf2f(xr[256 + j]);
            float pu = acc[mf][2][jj][r] + brow[512 + j] + bf2f(xr[512 + j]);
            float pf = acc[mf][3][jj][r] + brow[768 + j] + bf2f(xr[768 + j]);
            float gi_ = sigm(pi), go = sigm(po), gu = tanh_(pu), gf = sigm(pf);
            float c = gi_ * gu + gf * scv[jj];
            float h = go * tanh_(c);
            cells[ob + j] = c;
            hidd[ob + j]  = h;
          }
        }
      __syncthreads();   // h/c stores drained before next level's gather
    }
  }
}

// ---------------------------------------------------------------------------
extern "C" void kernel_launch(void* const* d_in, const int* in_sizes, int n_in,
                              void* d_out, int out_size, void* d_ws, size_t ws_size,
                              hipStream_t stream) {
  Params p;
  p.inputs = (const float*)d_in[0];
  const int* parents = (const int*)d_in[2];
  for (int d = 0; d < 2; ++d) {
    int o = 3 + d * 8;
    p.ioux_w[d] = (const float*)d_in[o + 0];
    p.ioux_b[d] = (const float*)d_in[o + 1];
    p.iouh_w[d] = (const float*)d_in[o + 2];
    p.iouh_b[d] = (const float*)d_in[o + 3];
    p.fx_w[d]   = (const float*)d_in[o + 4];
    p.fx_b[d]   = (const float*)d_in[o + 5];
    p.fh_w[d]   = (const float*)d_in[o + 6];
    p.fh_b[d]   = (const float*)d_in[o + 7];
  }

  unsigned short* a16   = (unsigned short*)d_ws;        // 8,388,608 u16
  unsigned short* w16x  = a16 + 8388608u;               // 524,288
  unsigned short* w16h  = w16x + 524288u;               // 524,288 (fragment layout)
  unsigned short* xp    = w16h + 524288u;               // 67,108,864
  unsigned short* A16ws = xp + 67108864u;               // 16,777,216 (unused)
  float* bias = (float*)(A16ws + 16777216u);            // 2048 f32
  int*   lev_g   = (int*)(bias + 2048u);                // 65,536
  int*   csr_off = lev_g + 65536;                       // 33,280
  int*   csr_dat = csr_off + 33280;                     // 32,768
  int*   lvcnt   = csr_dat + 32768;                     // 96

  float* cells = (float*)d_out;                         // [256][128][512]
  float* hidd  = cells + 16777216u;

  prep_kernel<<<dim3(1024), dim3(256), 0, stream>>>(p, a16, w16x, w16h, bias, lvcnt);
  levels_kernel<<<dim3(128), dim3(256), 0, stream>>>(parents, lev_g, csr_off, csr_dat, lvcnt);
  xproj_gemm<<<dim3(256, 16), dim3(256), 0, stream>>>(a16, w16x, xp);
  tree_fused<<<dim3(128, 2), dim3(256), 0, stream>>>(lev_g, csr_off, csr_dat,
      parents, w16h, bias, xp, cells, hidd);
}